// Round 1
// baseline (639.598 us; speedup 1.0000x reference)
//
#include <hip/hip_runtime.h>
#include <math.h>

#define N_PTS 8192
#define D_FEAT 768

typedef float v2f __attribute__((ext_vector_type(2)));

// ---- wave64 reductions via DPP (row_shr 1,2,4,8 + row_bcast15, row_bcast31) ----
__device__ __forceinline__ float wred_max_f32(float x) {   // x >= 0 required (identity 0)
    int v = __float_as_int(x), o;
    o = __builtin_amdgcn_update_dpp(0, v, 0x111, 0xf, 0xf, false); v = __float_as_int(fmaxf(__int_as_float(v), __int_as_float(o)));
    o = __builtin_amdgcn_update_dpp(0, v, 0x112, 0xf, 0xf, false); v = __float_as_int(fmaxf(__int_as_float(v), __int_as_float(o)));
    o = __builtin_amdgcn_update_dpp(0, v, 0x114, 0xf, 0xf, false); v = __float_as_int(fmaxf(__int_as_float(v), __int_as_float(o)));
    o = __builtin_amdgcn_update_dpp(0, v, 0x118, 0xf, 0xf, false); v = __float_as_int(fmaxf(__int_as_float(v), __int_as_float(o)));
    o = __builtin_amdgcn_update_dpp(0, v, 0x142, 0xa, 0xf, false); v = __float_as_int(fmaxf(__int_as_float(v), __int_as_float(o)));
    o = __builtin_amdgcn_update_dpp(0, v, 0x143, 0xc, 0xf, false); v = __float_as_int(fmaxf(__int_as_float(v), __int_as_float(o)));
    return __int_as_float(__builtin_amdgcn_readlane(v, 63));
}
__device__ __forceinline__ int wred_min_i32(int x) {       // x >= 0 (identity INT_MAX)
    int v = x, o;
    o = __builtin_amdgcn_update_dpp(0x7fffffff, v, 0x111, 0xf, 0xf, false); v = (o < v) ? o : v;
    o = __builtin_amdgcn_update_dpp(0x7fffffff, v, 0x112, 0xf, 0xf, false); v = (o < v) ? o : v;
    o = __builtin_amdgcn_update_dpp(0x7fffffff, v, 0x114, 0xf, 0xf, false); v = (o < v) ? o : v;
    o = __builtin_amdgcn_update_dpp(0x7fffffff, v, 0x118, 0xf, 0xf, false); v = (o < v) ? o : v;
    o = __builtin_amdgcn_update_dpp(0x7fffffff, v, 0x142, 0xa, 0xf, false); v = (o < v) ? o : v;
    o = __builtin_amdgcn_update_dpp(0x7fffffff, v, 0x143, 0xc, 0xf, false); v = (o < v) ? o : v;
    return __builtin_amdgcn_readlane(v, 63);
}
__device__ __forceinline__ float wred_add_f32(float x) {   // identity 0
    int v = __float_as_int(x), o;
    o = __builtin_amdgcn_update_dpp(0, v, 0x111, 0xf, 0xf, false); v = __float_as_int(__int_as_float(v) + __int_as_float(o));
    o = __builtin_amdgcn_update_dpp(0, v, 0x112, 0xf, 0xf, false); v = __float_as_int(__int_as_float(v) + __int_as_float(o));
    o = __builtin_amdgcn_update_dpp(0, v, 0x114, 0xf, 0xf, false); v = __float_as_int(__int_as_float(v) + __int_as_float(o));
    o = __builtin_amdgcn_update_dpp(0, v, 0x118, 0xf, 0xf, false); v = __float_as_int(__int_as_float(v) + __int_as_float(o));
    o = __builtin_amdgcn_update_dpp(0, v, 0x142, 0xa, 0xf, false); v = __float_as_int(__int_as_float(v) + __int_as_float(o));
    o = __builtin_amdgcn_update_dpp(0, v, 0x143, 0xc, 0xf, false); v = __float_as_int(__int_as_float(v) + __int_as_float(o));
    return __int_as_float(__builtin_amdgcn_readlane(v, 63));
}

// u64 max-merge DPP step: compiler lowers the compare to one v_cmp_lt_u64.
// identity 0 loses to any real key (keys always have lo = ~idx > 0).
#define DPP64_STEP(cur, ctrl, rmask)                                                        \
    {                                                                                       \
        unsigned _h = (unsigned)__builtin_amdgcn_update_dpp(0, (int)(unsigned)((cur) >> 32), ctrl, rmask, 0xf, false); \
        unsigned _l = (unsigned)__builtin_amdgcn_update_dpp(0, (int)(unsigned)(cur), ctrl, rmask, 0xf, false);         \
        unsigned long long _o = ((unsigned long long)_h << 32) | _l;                        \
        cur = (_o > (cur)) ? _o : (cur);                                                    \
    }

// ---------------- FPS + global/component safety: one block per batch ----------------
// ROUND 9 deltas vs r8 (all selection-exact):
//  - update loop runs on <2 x float> pairs (points 2j/2j+1) -> v_pk_add/mul_f32
//    at f32x2 rate; per-element op order ((dx*dx+dy*dy)+dz*dz) unchanged,
//    contract still off -> bit-identical m2 values.
//  - sqrt-collapse guard counted via __ballot + __popcll (1 VALU/pt, popcount
//    on the scalar pipe). Since every thread counts its own max (c2 >= thi
//    always), OR(ncnt>=2) <=> sum(ncnt) > 64 -- proven-equivalent condition.
//  - first-index match: backward overwrite scan (2 instr/pt) instead of the
//    cmp/select/min tree (~3/pt).
//  - speculative winner-coords load served from a 128 KiB LDS float4 table
//    (copied once at init) instead of global: ~120cy ds_read vs 200-350cy
//    L1-thrash/L2 global on the serial tail. Values are bit-identical copies.
__global__ __launch_bounds__(256, 1) __attribute__((amdgpu_waves_per_eu(1)))
void fps_kernel(const float* __restrict__ coords,
                int* __restrict__ idx_all,
                float* __restrict__ safety_all) {
#pragma clang fp contract(off)
    const int b = blockIdx.x;         // 0..1
    const int t = threadIdx.x;
    const float* cb = coords + (size_t)b * N_PTS * 3;

    v2f px2[16], py2[16], pz2[16], m2p[16];
#pragma unroll
    for (int j = 0; j < 16; j++) {
        int p0 = t + (2 * j) * 256, p1 = t + (2 * j + 1) * 256;
        px2[j].x = cb[p0 * 3 + 0]; px2[j].y = cb[p1 * 3 + 0];
        py2[j].x = cb[p0 * 3 + 1]; py2[j].y = cb[p1 * 3 + 1];
        pz2[j].x = cb[p0 * 3 + 2]; pz2[j].y = cb[p1 * 3 + 2];
        m2p[j].x = INFINITY; m2p[j].y = INFINITY;
    }
    __shared__ float cbl4[N_PTS * 4];           // 128 KiB coord table, float4 stride
    __shared__ unsigned long long skey[2][4];
    __shared__ int sel[256];
    __shared__ float r1s[4], r2s[4];
#pragma unroll
    for (int j = 0; j < 16; j++) {
        int p0 = t + (2 * j) * 256, p1 = t + (2 * j + 1) * 256;
        *(float4*)&cbl4[p0 * 4] = make_float4(px2[j].x, py2[j].x, pz2[j].x, 0.f);
        *(float4*)&cbl4[p1 * 4] = make_float4(px2[j].y, py2[j].y, pz2[j].y, 0.f);
    }
    if (t == 0) sel[0] = 0;
    float lx = cb[0], ly = cb[1], lz = cb[2];   // center 0 (uniform broadcast load)
    __syncthreads();

    const int lane = t & 63, w = t >> 6;
    for (int i = 1; i < 256; i++) {
        // --- branch-free d2-domain update, packed f32x2 (numpy op order per half) ---
        v2f Lx = {lx, lx}, Ly = {ly, ly}, Lz = {lz, lz};
#pragma unroll
        for (int j = 0; j < 16; j++) {
            v2f dx = px2[j] - Lx, dy = py2[j] - Ly, dz = pz2[j] - Lz;
            v2f d2 = dx * dx + dy * dy + dz * dz;      // ((dx^2+dy^2)+dz^2), no fma
            m2p[j] = __builtin_elementwise_min(m2p[j], d2);
        }
        // --- per-thread max via balanced tree (order-independent for non-NaN) ---
        v2f q[8];
#pragma unroll
        for (int j = 0; j < 8; j++) q[j] = __builtin_elementwise_max(m2p[j], m2p[j + 8]);
#pragma unroll
        for (int j = 0; j < 4; j++) q[j] = __builtin_elementwise_max(q[j], q[j + 4]);
        q[0] = __builtin_elementwise_max(q[0], q[2]);
        q[1] = __builtin_elementwise_max(q[1], q[3]);
        q[0] = __builtin_elementwise_max(q[0], q[1]);
        float c2 = fmaxf(q[0].x, q[0].y);
        // --- first index achieving c2: backward overwrite scan (last write = min k) ---
        int bk = 0;
#pragma unroll
        for (int j = 15; j >= 0; j--) {
            bk = (m2p[j].y == c2) ? (2 * j + 1) : bk;
            bk = (m2p[j].x == c2) ? (2 * j) : bk;
        }
        // sqrt-collapse guard: >=2 entries within relative 5e-7 band of a thread's
        // own max -> rounded sqrts could tie across distinct d2 -> rare exact path.
        // Every thread counts its own max (c2 >= thi for c2 >= 0), so
        // any(ncnt>=2) <=> total > 64. Ballot = 1 v_cmp/pt, popcount on SALU pipe.
        float thi = c2 * 0.9999995f;
        int tot = 0;
#pragma unroll
        for (int j = 0; j < 16; j++) {
            tot += __popcll(__ballot(m2p[j].x >= thi));
            tot += __popcll(__ballot(m2p[j].y >= thi));
        }
        float smax;
        if (tot > 64) {               // rare wave-uniform slow path (exact)
            smax = -1.f; bk = 0;
#pragma unroll
            for (int k = 0; k < 32; k++) {
                float mk = (k & 1) ? m2p[k >> 1].y : m2p[k >> 1].x;   // static idx (unrolled)
                float s = sqrtf(mk);
                if (s > smax) { smax = s; bk = k; }
            }
        } else {
            smax = sqrtf(c2);         // one correctly-rounded sqrt per thread
        }
        int bi = t + bk * 256;
        // --- wave reduce on packed u64 key: (value desc, index asc) ---
        unsigned long long key = ((unsigned long long)__float_as_uint(smax) << 32)
                               | (unsigned)(0xFFFFFFFFu - (unsigned)bi);
        DPP64_STEP(key, 0x111, 0xf)    // row_shr1
        DPP64_STEP(key, 0x112, 0xf)    // row_shr2
        DPP64_STEP(key, 0x114, 0xf)    // row_shr4
        DPP64_STEP(key, 0x118, 0xf)    // row_shr8
        DPP64_STEP(key, 0x142, 0xa)    // row_bcast15
        DPP64_STEP(key, 0x143, 0xc)    // row_bcast31
        if (lane == 63) skey[i & 1][w] = key;
        __syncthreads();   // LDS-only before barrier -> cheap lgkm drain
        const int par = i & 1;
        // --- read 4 wave records; speculatively load ALL candidates' coords (LDS) ---
        unsigned long long k8 = skey[par][lane & 3];
        int cidx = (int)(0xFFFFFFFFu - (unsigned)k8);   // candidate of record lane&3
        float spec = 0.f;
        if (lane < 12) spec = cbl4[cidx * 4 + (lane >> 2)];  // ds_read, covers 4x xyz
        // --- combine over 4 records (overlaps the LDS load) ---
        DPP64_STEP(k8, 0x111, 0xf)
        DPP64_STEP(k8, 0x112, 0xf)     // lane 3 = max of records 0..3
        unsigned klo = (unsigned)__builtin_amdgcn_readlane((int)(unsigned)k8, 3);
        int fbi = (int)(0xFFFFFFFFu - klo);             // uniform (SGPR)
        int ww = (fbi & 255) >> 6;                      // winning wave / record
        // winner coords from the speculative lanes: rec=ww, comp c at lane c*4+ww
        lx = __int_as_float(__builtin_amdgcn_readlane(__float_as_int(spec), ww));
        ly = __int_as_float(__builtin_amdgcn_readlane(__float_as_int(spec), 4 + ww));
        lz = __int_as_float(__builtin_amdgcn_readlane(__float_as_int(spec), 8 + ww));
        if (t == 0) sel[i] = fbi;     // LDS only
        // NOTE: no explicit zeroing of the winner: next update gives d2=0 exactly.
    }

    // ---- tail: write indices once (oc/od are prefixes of og) ----
    __syncthreads();
    {
        int v = sel[t];
        idx_all[b * 256 + t] = v;                    // og
        if (t < 128) idx_all[512 + b * 128 + t] = v; // oc
        if (t < 64)  idx_all[768 + b * 64 + t] = v;  // od
    }

    // ---- tail: global & component safety (z in registers; original k-order sums) ----
    float s1 = 0.f, s2 = 0.f;
#pragma unroll
    for (int j = 0; j < 16; j++) {
        s1 += pz2[j].x; s2 += pz2[j].x * pz2[j].x;   // k = 2j
        s1 += pz2[j].y; s2 += pz2[j].y * pz2[j].y;   // k = 2j+1
    }
    s1 = wred_add_f32(s1);
    s2 = wred_add_f32(s2);
    if (lane == 0) { r1s[w] = s1; r2s[w] = s2; }
    __syncthreads();
    float S1 = r1s[0] + r1s[1] + r1s[2] + r1s[3];
    float S2 = r2s[0] + r2s[1] + r2s[2] + r2s[3];
    float mean = S1 / 8192.0f;
    float var1 = (S2 - S1 * S1 / 8192.0f) / 8191.0f;     // ddof=1
    float scomp = 1.0f + expf(-var1 / 0.1f) * 0.9f;      // component safety
    {
        int p = sel[t];
        float z = cbl4[p * 4 + 2];                       // bit-identical copy of cb[p*3+2]
        safety_all[b * 256 + t] = 1.0f + (1.0f / (1.0f + expf(-((z - mean) / 5.0f)))) * 0.95f;
    }
    if (t < 128) safety_all[512 + b * 128 + t] = scomp;
}

// ---------------- per-scale score MLP (+ detail density folded in) ----------------
__global__ __launch_bounds__(256) void score_kernel(
    const float* __restrict__ feat, const float* __restrict__ coords,
    const float* __restrict__ gW1, const float* __restrict__ gb1,
    const float* __restrict__ gW2, const float* __restrict__ gb2,
    const float* __restrict__ cW1, const float* __restrict__ cb1,
    const float* __restrict__ cW2, const float* __restrict__ cb2,
    const float* __restrict__ dW1, const float* __restrict__ db1,
    const float* __restrict__ dW2, const float* __restrict__ db2,
    const int* __restrict__ idx_all, const float* __restrict__ safety_all,
    float* __restrict__ final_all) {
    int bid = blockIdx.x;
    int b, c0, C, S, off;
    const float *W1, *b1, *W2, *b2;
    if (bid < 64)      { C = 256; S = 16; W1 = gW1; b1 = gb1; W2 = gW2; b2 = gb2; b = bid >> 5; c0 = (bid & 31) * 8; off = 0; }
    else if (bid < 96) { int r = bid - 64; C = 128; S = 16; W1 = cW1; b1 = cb1; W2 = cW2; b2 = cb2; b = r >> 4; c0 = (r & 15) * 8; off = 512; }
    else               { int r = bid - 96; C = 64;  S = 8;  W1 = dW1; b1 = db1; W2 = dW2; b2 = db2; b = r >> 3; c0 = (r & 7) * 8; off = 768; }
    const bool isdet = (bid >= 96);

    __shared__ float xt[8 * 772];
    __shared__ float h1s[8 * 260];
    __shared__ float ps[8 * 16];
    __shared__ int pid[8];
    __shared__ float dpart[4][8];
    __shared__ float sdens[8];
    const int t = threadIdx.x;
    if (t < 8) pid[t] = idx_all[off + b * C + c0 + t];
    __syncthreads();

    if (isdet) {
#pragma clang fp contract(off)
        float cx[8], cy[8], cz[8], cc[8];
#pragma unroll
        for (int c = 0; c < 8; c++) {
            const float* cp = coords + ((size_t)b * N_PTS + pid[c]) * 3;
            cx[c] = cp[0]; cy[c] = cp[1]; cz[c] = cp[2];
            cc[c] = cx[c] * cx[c] + cy[c] * cy[c] + cz[c] * cz[c];
        }
        int cnt[8];
#pragma unroll
        for (int c = 0; c < 8; c++) cnt[c] = 0;
        const float* cbl = coords + (size_t)b * N_PTS * 3;
        for (int k = 0; k < 32; k++) {
            int q = t + k * 256;
            float x = cbl[q * 3], y = cbl[q * 3 + 1], z = cbl[q * 3 + 2];
            float pp = x * x + y * y + z * z;
#pragma unroll
            for (int c = 0; c < 8; c++) {
                float dot = cx[c] * x + cy[c] * y + cz[c] * z;
                float d2 = (cc[c] + pp) - 2.0f * dot;   // same formula/order as reference
                if (d2 < 0.25f) cnt[c]++;
            }
        }
        int wv = t >> 6;
#pragma unroll
        for (int c = 0; c < 8; c++) {
            float s = wred_add_f32((float)cnt[c]);      // integer counts: exact in f32
            if ((t & 63) == 0) dpart[wv][c] = s;
        }
    }

    for (int r = 0; r < 8; r++) {
        const float* src = feat + ((size_t)b * N_PTS + pid[r]) * D_FEAT;
        for (int c = t; c < 768; c += 256) xt[r * 772 + c] = src[c];
    }
    __syncthreads();
    if (isdet && t < 8) {
        float tot = dpart[0][t] + dpart[1][t] + dpart[2][t] + dpart[3][t];
        sdens[t] = 1.0f + (tot / 8192.0f) * 0.95f;
    }

    {
        int rp = t & 3;
        int jg = t >> 2;
        int r0 = rp * 2;
        if (jg * 4 < C) {
            float4 acc0[4], acc1[4];
#pragma unroll
            for (int a = 0; a < 4; a++) { acc0[a] = make_float4(0, 0, 0, 0); acc1[a] = make_float4(0, 0, 0, 0); }
            for (int k = 0; k < 768; k += 4) {
                float4 x0 = *(const float4*)&xt[r0 * 772 + k];
                float4 x1 = *(const float4*)&xt[(r0 + 1) * 772 + k];
#pragma unroll
                for (int a = 0; a < 4; a++) {
                    int j = jg * 4 + a;
                    float4 wv = *(const float4*)&W1[(size_t)j * 768 + k];
                    acc0[a].x = fmaf(wv.x, x0.x, acc0[a].x); acc0[a].y = fmaf(wv.y, x0.y, acc0[a].y);
                    acc0[a].z = fmaf(wv.z, x0.z, acc0[a].z); acc0[a].w = fmaf(wv.w, x0.w, acc0[a].w);
                    acc1[a].x = fmaf(wv.x, x1.x, acc1[a].x); acc1[a].y = fmaf(wv.y, x1.y, acc1[a].y);
                    acc1[a].z = fmaf(wv.z, x1.z, acc1[a].z); acc1[a].w = fmaf(wv.w, x1.w, acc1[a].w);
                }
            }
#pragma unroll
            for (int a = 0; a < 4; a++) {
                int j = jg * 4 + a;
                float bb = b1[j];
                float v0 = (acc0[a].x + acc0[a].y) + (acc0[a].z + acc0[a].w) + bb;
                float v1 = (acc1[a].x + acc1[a].y) + (acc1[a].z + acc1[a].w) + bb;
                h1s[r0 * 260 + j]       = fmaxf(v0, 0.f);
                h1s[(r0 + 1) * 260 + j] = fmaxf(v1, 0.f);
            }
        }
    }
    __syncthreads();

    if (t < 8 * S) {
        int r = t / S, s = t % S;
        float4 a = make_float4(0, 0, 0, 0);
        for (int k = 0; k < C; k += 4) {
            float4 wv = *(const float4*)&W2[s * C + k];
            float4 h = *(const float4*)&h1s[r * 260 + k];
            a.x = fmaf(wv.x, h.x, a.x); a.y = fmaf(wv.y, h.y, a.y);
            a.z = fmaf(wv.z, h.z, a.z); a.w = fmaf(wv.w, h.w, a.w);
        }
        float logit = (a.x + a.y) + (a.z + a.w) + b2[s];
        ps[r * 16 + s] = 1.0f / (1.0f + expf(-logit));
    }
    __syncthreads();
    if (t < 8) {
        float m = 0.f;
        for (int s = 0; s < S; s++) m += ps[t * 16 + s];
        m /= (float)S;
        float saf = isdet ? sdens[t] : safety_all[off + b * C + c0 + t];
        final_all[off + b * C + c0 + t] = m * saf;
    }
}

// ---------------- final MLP + LayerNorm, with per-block redundant top-k ----------------
__global__ __launch_bounds__(256) void final_kernel(
    const float* __restrict__ feat, const int* __restrict__ idx_all,
    const float* __restrict__ final_all,
    const float* __restrict__ pW1, const float* __restrict__ pb1,
    const float* __restrict__ pW2, const float* __restrict__ pb2,
    const float* __restrict__ lng, const float* __restrict__ lnb,
    float* __restrict__ out) {
    int bid = blockIdx.x;               // 40 blocks
    int b = bid / 20, pr = bid % 20;
    int t = threadIdx.x;
    __shared__ float xt[2 * 772];
    __shared__ float h1s[2 * 388];
    __shared__ float red[16];
    __shared__ int tokp[2];

    int scale = (pr < 8) ? 0 : (pr < 16) ? 1 : 2;
    int C    = (scale == 0) ? 256 : (scale == 1) ? 128 : 64;
    int off  = (scale == 0) ? 0 : (scale == 1) ? 512 : 768;
    int base = (scale == 0) ? 0 : (scale == 1) ? 8 : 16;   // in block units
    int r0 = (pr - base) * 2;           // rank of first token within scale

    if (t < 64) {                       // wave 0 does the top-k
        float v[4];
#pragma unroll
        for (int j = 0; j < 4; j++) {
            int ii = t + j * 64;
            v[j] = (ii < C) ? final_all[off + b * C + ii] : -INFINITY;
        }
        for (int s = 0; s <= r0 + 1; s++) {
            float bd = v[0]; int bj = 0;
#pragma unroll
            for (int j = 1; j < 4; j++) if (v[j] > bd) { bd = v[j]; bj = j; }
            int bi2 = t + bj * 64;
            float m = wred_max_f32(bd);          // scores > 0, identity 0 safe
            int cand = (bd == m) ? bi2 : 0x7fffffff;
            int wi = wred_min_i32(cand);         // first-index tie-break = lax.top_k
            if (t == (wi & 63)) {
#pragma unroll
                for (int j = 0; j < 4; j++) if (j == (wi >> 6)) v[j] = -INFINITY;
            }
            if (t == 0) {
                if (s == r0)     tokp[0] = idx_all[off + b * C + wi];
                if (s == r0 + 1) tokp[1] = idx_all[off + b * C + wi];
            }
        }
    }
    __syncthreads();

    for (int r = 0; r < 2; r++) {
        int p = tokp[r];
        const float* src = feat + ((size_t)b * N_PTS + p) * D_FEAT;
        for (int c = t; c < 768; c += 256) xt[r * 772 + c] = src[c];
    }
    __syncthreads();

    for (int u = t; u < 768; u += 256) {
        int j = u >> 1, r = u & 1;
        float4 a = make_float4(0, 0, 0, 0);
        for (int k = 0; k < 768; k += 4) {
            float4 wv = *(const float4*)&pW1[(size_t)j * 768 + k];
            float4 x = *(const float4*)&xt[r * 772 + k];
            a.x = fmaf(wv.x, x.x, a.x); a.y = fmaf(wv.y, x.y, a.y);
            a.z = fmaf(wv.z, x.z, a.z); a.w = fmaf(wv.w, x.w, a.w);
        }
        float v = (a.x + a.y) + (a.z + a.w) + pb1[j];
        h1s[r * 388 + j] = fmaxf(v, 0.f);
    }
    __syncthreads();

    for (int u = t; u < 1536; u += 256) {
        int o = u >> 1, r = u & 1;
        float4 a = make_float4(0, 0, 0, 0);
        for (int k = 0; k < 384; k += 4) {
            float4 wv = *(const float4*)&pW2[(size_t)o * 384 + k];
            float4 h = *(const float4*)&h1s[r * 388 + k];
            a.x = fmaf(wv.x, h.x, a.x); a.y = fmaf(wv.y, h.y, a.y);
            a.z = fmaf(wv.z, h.z, a.z); a.w = fmaf(wv.w, h.w, a.w);
        }
        xt[r * 772 + o] = (a.x + a.y) + (a.z + a.w) + pb2[o];
    }
    __syncthreads();

    for (int r = 0; r < 2; r++) {
        float s1 = 0.f, s2 = 0.f;
        for (int o = t; o < 768; o += 256) { float v = xt[r * 772 + o]; s1 += v; s2 += v * v; }
#pragma unroll
        for (int off2 = 32; off2 >= 1; off2 >>= 1) {
            s1 += __shfl_down(s1, off2, 64);
            s2 += __shfl_down(s2, off2, 64);
        }
        int lane = t & 63, wid = t >> 6;
        if (lane == 0) { red[wid * 2] = s1; red[wid * 2 + 1] = s2; }
        __syncthreads();
        float S1 = red[0] + red[2] + red[4] + red[6];
        float S2 = red[1] + red[3] + red[5] + red[7];
        float mu = S1 / 768.0f;
        float var = S2 / 768.0f - mu * mu;
        float inv = rsqrtf(var + 1e-5f);
        float* dst = out + ((size_t)b * 40 + pr * 2 + r) * 768;
        for (int o = t; o < 768; o += 256) {
            float v = xt[r * 772 + o];
            dst[o] = (v - mu) * inv * lng[o] + lnb[o];
        }
        __syncthreads();
    }
}

extern "C" void kernel_launch(void* const* d_in, const int* in_sizes, int n_in,
                              void* d_out, int out_size, void* d_ws, size_t ws_size,
                              hipStream_t stream) {
    const float* feat   = (const float*)d_in[0];
    const float* coords = (const float*)d_in[1];
    const float* gW1 = (const float*)d_in[2],  *gb1 = (const float*)d_in[3];
    const float* gW2 = (const float*)d_in[4],  *gb2 = (const float*)d_in[5];
    const float* cW1 = (const float*)d_in[6],  *cb1 = (const float*)d_in[7];
    const float* cW2 = (const float*)d_in[8],  *cb2 = (const float*)d_in[9];
    const float* dW1 = (const float*)d_in[10], *db1 = (const float*)d_in[11];
    const float* dW2 = (const float*)d_in[12], *db2 = (const float*)d_in[13];
    const float* pW1 = (const float*)d_in[14], *pb1 = (const float*)d_in[15];
    const float* pW2 = (const float*)d_in[16], *pb2 = (const float*)d_in[17];
    const float* lng = (const float*)d_in[18], *lnb = (const float*)d_in[19];
    float* out = (float*)d_out;

    int*   idx_all    = (int*)d_ws;               // 896 ints
    float* safety_all = (float*)d_ws + 896;       // 768 floats used
    float* final_all  = (float*)d_ws + 1792;      // 896 floats

    fps_kernel<<<2, 256, 0, stream>>>(coords, idx_all, safety_all);
    score_kernel<<<112, 256, 0, stream>>>(feat, coords, gW1, gb1, gW2, gb2, cW1, cb1, cW2, cb2,
                                          dW1, db1, dW2, db2, idx_all, safety_all, final_all);
    final_kernel<<<40, 256, 0, stream>>>(feat, idx_all, final_all, pW1, pb1, pW2, pb2, lng, lnb, out);
}

// Round 2
// 558.033 us; speedup vs baseline: 1.1462x; 1.1462x over previous
//
#include <hip/hip_runtime.h>
#include <math.h>

#define N_PTS 8192
#define D_FEAT 768

typedef float v2f __attribute__((ext_vector_type(2)));

// ---- wave64 reductions via DPP (row_shr 1,2,4,8 + row_bcast15, row_bcast31) ----
__device__ __forceinline__ float wred_max_f32(float x) {   // x >= 0 required (identity 0)
    int v = __float_as_int(x), o;
    o = __builtin_amdgcn_update_dpp(0, v, 0x111, 0xf, 0xf, false); v = __float_as_int(fmaxf(__int_as_float(v), __int_as_float(o)));
    o = __builtin_amdgcn_update_dpp(0, v, 0x112, 0xf, 0xf, false); v = __float_as_int(fmaxf(__int_as_float(v), __int_as_float(o)));
    o = __builtin_amdgcn_update_dpp(0, v, 0x114, 0xf, 0xf, false); v = __float_as_int(fmaxf(__int_as_float(v), __int_as_float(o)));
    o = __builtin_amdgcn_update_dpp(0, v, 0x118, 0xf, 0xf, false); v = __float_as_int(fmaxf(__int_as_float(v), __int_as_float(o)));
    o = __builtin_amdgcn_update_dpp(0, v, 0x142, 0xa, 0xf, false); v = __float_as_int(fmaxf(__int_as_float(v), __int_as_float(o)));
    o = __builtin_amdgcn_update_dpp(0, v, 0x143, 0xc, 0xf, false); v = __float_as_int(fmaxf(__int_as_float(v), __int_as_float(o)));
    return __int_as_float(__builtin_amdgcn_readlane(v, 63));
}
__device__ __forceinline__ int wred_min_i32(int x) {       // x >= 0 (identity INT_MAX)
    int v = x, o;
    o = __builtin_amdgcn_update_dpp(0x7fffffff, v, 0x111, 0xf, 0xf, false); v = (o < v) ? o : v;
    o = __builtin_amdgcn_update_dpp(0x7fffffff, v, 0x112, 0xf, 0xf, false); v = (o < v) ? o : v;
    o = __builtin_amdgcn_update_dpp(0x7fffffff, v, 0x114, 0xf, 0xf, false); v = (o < v) ? o : v;
    o = __builtin_amdgcn_update_dpp(0x7fffffff, v, 0x118, 0xf, 0xf, false); v = (o < v) ? o : v;
    o = __builtin_amdgcn_update_dpp(0x7fffffff, v, 0x142, 0xa, 0xf, false); v = (o < v) ? o : v;
    o = __builtin_amdgcn_update_dpp(0x7fffffff, v, 0x143, 0xc, 0xf, false); v = (o < v) ? o : v;
    return __builtin_amdgcn_readlane(v, 63);
}
__device__ __forceinline__ float wred_add_f32(float x) {   // identity 0
    int v = __float_as_int(x), o;
    o = __builtin_amdgcn_update_dpp(0, v, 0x111, 0xf, 0xf, false); v = __float_as_int(__int_as_float(v) + __int_as_float(o));
    o = __builtin_amdgcn_update_dpp(0, v, 0x112, 0xf, 0xf, false); v = __float_as_int(__int_as_float(v) + __int_as_float(o));
    o = __builtin_amdgcn_update_dpp(0, v, 0x114, 0xf, 0xf, false); v = __float_as_int(__int_as_float(v) + __int_as_float(o));
    o = __builtin_amdgcn_update_dpp(0, v, 0x118, 0xf, 0xf, false); v = __float_as_int(__int_as_float(v) + __int_as_float(o));
    o = __builtin_amdgcn_update_dpp(0, v, 0x142, 0xa, 0xf, false); v = __float_as_int(__int_as_float(v) + __int_as_float(o));
    o = __builtin_amdgcn_update_dpp(0, v, 0x143, 0xc, 0xf, false); v = __float_as_int(__int_as_float(v) + __int_as_float(o));
    return __int_as_float(__builtin_amdgcn_readlane(v, 63));
}

// u64 max-merge DPP step: compiler lowers the compare to one v_cmp_lt_u64.
// identity 0 loses to any real key (keys always have lo = ~idx > 0).
#define DPP64_STEP(cur, ctrl, rmask)                                                        \
    {                                                                                       \
        unsigned _h = (unsigned)__builtin_amdgcn_update_dpp(0, (int)(unsigned)((cur) >> 32), ctrl, rmask, 0xf, false); \
        unsigned _l = (unsigned)__builtin_amdgcn_update_dpp(0, (int)(unsigned)(cur), ctrl, rmask, 0xf, false);         \
        unsigned long long _o = ((unsigned long long)_h << 32) | _l;                        \
        cur = (_o > (cur)) ? _o : (cur);                                                    \
    }

// ---------------- FPS + global/component safety: one block per batch ----------------
// ROUND 10 deltas vs r9 (all selection-exact):
//  - 512 threads (8 waves, 2/SIMD): 16 pts/thread instead of 32. Total VALU
//    work unchanged, but each SIMD now holds TWO waves, so dependent-op
//    latency (DPP chains, sqrt, LDS reads) interleaves with the sibling
//    wave's issue instead of being raw wall time. r9 post-mortem: at 1
//    wave/SIMD ~60% of iteration time was exposed stall.
//  - match via r8's parallel cmp/select + min tree (depth 5) -- r9's serial
//    backward cndmask scan was a ~128cy dependent chain on the critical path.
//  - kept from r9: packed v2f update (VALUBusy evidence it works), ballot
//    guard (equivalent condition, cheaper), LDS float4 coord table for the
//    speculative winner load.
//  - cross-wave combine over 8 records (3 DPP64 steps, lane 7 holds max).
__global__ __launch_bounds__(512, 2) __attribute__((amdgpu_waves_per_eu(2)))
void fps_kernel(const float* __restrict__ coords,
                int* __restrict__ idx_all,
                float* __restrict__ safety_all) {
#pragma clang fp contract(off)
    const int b = blockIdx.x;         // 0..1
    const int t = threadIdx.x;        // 0..511
    const float* cb = coords + (size_t)b * N_PTS * 3;

    v2f px2[8], py2[8], pz2[8], m2p[8];
#pragma unroll
    for (int j = 0; j < 8; j++) {
        int p0 = t + (2 * j) * 512, p1 = t + (2 * j + 1) * 512;
        px2[j].x = cb[p0 * 3 + 0]; px2[j].y = cb[p1 * 3 + 0];
        py2[j].x = cb[p0 * 3 + 1]; py2[j].y = cb[p1 * 3 + 1];
        pz2[j].x = cb[p0 * 3 + 2]; pz2[j].y = cb[p1 * 3 + 2];
        m2p[j].x = INFINITY; m2p[j].y = INFINITY;
    }
    __shared__ float cbl4[N_PTS * 4];           // 128 KiB coord table, float4 stride
    __shared__ unsigned long long skey[2][8];
    __shared__ int sel[256];
    __shared__ float r1s[8], r2s[8];
#pragma unroll
    for (int j = 0; j < 8; j++) {
        int p0 = t + (2 * j) * 512, p1 = t + (2 * j + 1) * 512;
        *(float4*)&cbl4[p0 * 4] = make_float4(px2[j].x, py2[j].x, pz2[j].x, 0.f);
        *(float4*)&cbl4[p1 * 4] = make_float4(px2[j].y, py2[j].y, pz2[j].y, 0.f);
    }
    if (t == 0) sel[0] = 0;
    float lx = cb[0], ly = cb[1], lz = cb[2];   // center 0 (uniform broadcast load)
    __syncthreads();

    const int lane = t & 63, w = t >> 6;        // wave 0..7
    for (int i = 1; i < 256; i++) {
        // --- branch-free d2-domain update, packed f32x2 (numpy op order per half) ---
        v2f Lx = {lx, lx}, Ly = {ly, ly}, Lz = {lz, lz};
#pragma unroll
        for (int j = 0; j < 8; j++) {
            v2f dx = px2[j] - Lx, dy = py2[j] - Ly, dz = pz2[j] - Lz;
            v2f d2 = dx * dx + dy * dy + dz * dz;      // ((dx^2+dy^2)+dz^2), no fma
            m2p[j] = __builtin_elementwise_min(m2p[j], d2);
        }
        // --- per-thread max via balanced tree (order-independent for non-NaN) ---
        v2f q[4];
#pragma unroll
        for (int j = 0; j < 4; j++) q[j] = __builtin_elementwise_max(m2p[j], m2p[j + 4]);
        q[0] = __builtin_elementwise_max(q[0], q[2]);
        q[1] = __builtin_elementwise_max(q[1], q[3]);
        q[0] = __builtin_elementwise_max(q[0], q[1]);
        float c2 = fmaxf(q[0].x, q[0].y);
        // --- first index achieving c2: parallel match + min tree (depth 5) ---
        int ci[8];
#pragma unroll
        for (int j = 0; j < 8; j++) {
            int a  = (m2p[j].x == c2) ? (2 * j)     : 0x7fff;
            int bb = (m2p[j].y == c2) ? (2 * j + 1) : 0x7fff;
            ci[j] = (a < bb) ? a : bb;
        }
#pragma unroll
        for (int j = 0; j < 4; j++) ci[j] = min(ci[j], ci[j + 4]);
        int bk = min(min(ci[0], ci[1]), min(ci[2], ci[3]));
        // sqrt-collapse guard: >=2 entries within relative 5e-7 band of a thread's
        // own max -> rounded sqrts could tie across distinct d2 -> rare exact path.
        // Every thread counts its own max (c2 >= thi for c2 >= 0), so per wave
        // any(ncnt>=2) <=> total > 64. Ballot = 1 v_cmp/pt, popcount on SALU.
        float thi = c2 * 0.9999995f;
        int tot = 0;
#pragma unroll
        for (int j = 0; j < 8; j++) {
            tot += __popcll(__ballot(m2p[j].x >= thi));
            tot += __popcll(__ballot(m2p[j].y >= thi));
        }
        float smax;
        if (tot > 64) {               // rare wave-uniform slow path (exact)
            smax = -1.f; bk = 0;
#pragma unroll
            for (int k = 0; k < 16; k++) {
                float mk = (k & 1) ? m2p[k >> 1].y : m2p[k >> 1].x;   // static idx (unrolled)
                float s = sqrtf(mk);
                if (s > smax) { smax = s; bk = k; }
            }
        } else {
            smax = sqrtf(c2);         // one correctly-rounded sqrt per thread
        }
        int bi = t + bk * 512;
        // --- wave reduce on packed u64 key: (value desc, index asc) ---
        unsigned long long key = ((unsigned long long)__float_as_uint(smax) << 32)
                               | (unsigned)(0xFFFFFFFFu - (unsigned)bi);
        DPP64_STEP(key, 0x111, 0xf)    // row_shr1
        DPP64_STEP(key, 0x112, 0xf)    // row_shr2
        DPP64_STEP(key, 0x114, 0xf)    // row_shr4
        DPP64_STEP(key, 0x118, 0xf)    // row_shr8
        DPP64_STEP(key, 0x142, 0xa)    // row_bcast15
        DPP64_STEP(key, 0x143, 0xc)    // row_bcast31
        if (lane == 63) skey[i & 1][w] = key;
        __syncthreads();   // LDS-only before barrier -> cheap lgkm drain
        const int par = i & 1;
        // --- read 8 wave records; speculatively load ALL candidates' coords (LDS) ---
        unsigned long long k8 = skey[par][lane & 7];
        int cidx = (int)(0xFFFFFFFFu - (unsigned)k8);   // candidate of record lane&7
        float spec = 0.f;
        if (lane < 24) spec = cbl4[cidx * 4 + (lane >> 3)];  // ds_read, covers 8x xyz
        // --- combine over 8 records (overlaps the LDS load) ---
        DPP64_STEP(k8, 0x111, 0xf)
        DPP64_STEP(k8, 0x112, 0xf)
        DPP64_STEP(k8, 0x114, 0xf)     // lane 7 = max of records 0..7
        unsigned klo = (unsigned)__builtin_amdgcn_readlane((int)(unsigned)k8, 7);
        int fbi = (int)(0xFFFFFFFFu - klo);             // uniform (SGPR)
        int ww = (fbi & 511) >> 6;                      // winning wave / record 0..7
        // winner coords from the speculative lanes: rec=ww, comp c at lane c*8+ww
        lx = __int_as_float(__builtin_amdgcn_readlane(__float_as_int(spec), ww));
        ly = __int_as_float(__builtin_amdgcn_readlane(__float_as_int(spec), 8 + ww));
        lz = __int_as_float(__builtin_amdgcn_readlane(__float_as_int(spec), 16 + ww));
        if (t == 0) sel[i] = fbi;     // LDS only
        // NOTE: no explicit zeroing of the winner: next update gives d2=0 exactly.
    }

    // ---- tail: write indices once (oc/od are prefixes of og) ----
    __syncthreads();
    if (t < 256) {
        int v = sel[t];
        idx_all[b * 256 + t] = v;                    // og
        if (t < 128) idx_all[512 + b * 128 + t] = v; // oc
        if (t < 64)  idx_all[768 + b * 64 + t] = v;  // od
    }

    // ---- tail: global & component safety (z in registers; k-order per thread) ----
    float s1 = 0.f, s2 = 0.f;
#pragma unroll
    for (int j = 0; j < 8; j++) {
        s1 += pz2[j].x; s2 += pz2[j].x * pz2[j].x;   // k = 2j
        s1 += pz2[j].y; s2 += pz2[j].y * pz2[j].y;   // k = 2j+1
    }
    s1 = wred_add_f32(s1);
    s2 = wred_add_f32(s2);
    if (lane == 0) { r1s[w] = s1; r2s[w] = s2; }
    __syncthreads();
    float S1 = ((r1s[0] + r1s[1]) + (r1s[2] + r1s[3])) + ((r1s[4] + r1s[5]) + (r1s[6] + r1s[7]));
    float S2 = ((r2s[0] + r2s[1]) + (r2s[2] + r2s[3])) + ((r2s[4] + r2s[5]) + (r2s[6] + r2s[7]));
    float mean = S1 / 8192.0f;
    float var1 = (S2 - S1 * S1 / 8192.0f) / 8191.0f;     // ddof=1
    float scomp = 1.0f + expf(-var1 / 0.1f) * 0.9f;      // component safety
    if (t < 256) {
        int p = sel[t];
        float z = cbl4[p * 4 + 2];                       // bit-identical copy of cb[p*3+2]
        safety_all[b * 256 + t] = 1.0f + (1.0f / (1.0f + expf(-((z - mean) / 5.0f)))) * 0.95f;
        if (t < 128) safety_all[512 + b * 128 + t] = scomp;
    }
}

// ---------------- per-scale score MLP (+ detail density folded in) ----------------
__global__ __launch_bounds__(256) void score_kernel(
    const float* __restrict__ feat, const float* __restrict__ coords,
    const float* __restrict__ gW1, const float* __restrict__ gb1,
    const float* __restrict__ gW2, const float* __restrict__ gb2,
    const float* __restrict__ cW1, const float* __restrict__ cb1,
    const float* __restrict__ cW2, const float* __restrict__ cb2,
    const float* __restrict__ dW1, const float* __restrict__ db1,
    const float* __restrict__ dW2, const float* __restrict__ db2,
    const int* __restrict__ idx_all, const float* __restrict__ safety_all,
    float* __restrict__ final_all) {
    int bid = blockIdx.x;
    int b, c0, C, S, off;
    const float *W1, *b1, *W2, *b2;
    if (bid < 64)      { C = 256; S = 16; W1 = gW1; b1 = gb1; W2 = gW2; b2 = gb2; b = bid >> 5; c0 = (bid & 31) * 8; off = 0; }
    else if (bid < 96) { int r = bid - 64; C = 128; S = 16; W1 = cW1; b1 = cb1; W2 = cW2; b2 = cb2; b = r >> 4; c0 = (r & 15) * 8; off = 512; }
    else               { int r = bid - 96; C = 64;  S = 8;  W1 = dW1; b1 = db1; W2 = dW2; b2 = db2; b = r >> 3; c0 = (r & 7) * 8; off = 768; }
    const bool isdet = (bid >= 96);

    __shared__ float xt[8 * 772];
    __shared__ float h1s[8 * 260];
    __shared__ float ps[8 * 16];
    __shared__ int pid[8];
    __shared__ float dpart[4][8];
    __shared__ float sdens[8];
    const int t = threadIdx.x;
    if (t < 8) pid[t] = idx_all[off + b * C + c0 + t];
    __syncthreads();

    if (isdet) {
#pragma clang fp contract(off)
        float cx[8], cy[8], cz[8], cc[8];
#pragma unroll
        for (int c = 0; c < 8; c++) {
            const float* cp = coords + ((size_t)b * N_PTS + pid[c]) * 3;
            cx[c] = cp[0]; cy[c] = cp[1]; cz[c] = cp[2];
            cc[c] = cx[c] * cx[c] + cy[c] * cy[c] + cz[c] * cz[c];
        }
        int cnt[8];
#pragma unroll
        for (int c = 0; c < 8; c++) cnt[c] = 0;
        const float* cbl = coords + (size_t)b * N_PTS * 3;
        for (int k = 0; k < 32; k++) {
            int q = t + k * 256;
            float x = cbl[q * 3], y = cbl[q * 3 + 1], z = cbl[q * 3 + 2];
            float pp = x * x + y * y + z * z;
#pragma unroll
            for (int c = 0; c < 8; c++) {
                float dot = cx[c] * x + cy[c] * y + cz[c] * z;
                float d2 = (cc[c] + pp) - 2.0f * dot;   // same formula/order as reference
                if (d2 < 0.25f) cnt[c]++;
            }
        }
        int wv = t >> 6;
#pragma unroll
        for (int c = 0; c < 8; c++) {
            float s = wred_add_f32((float)cnt[c]);      // integer counts: exact in f32
            if ((t & 63) == 0) dpart[wv][c] = s;
        }
    }

    for (int r = 0; r < 8; r++) {
        const float* src = feat + ((size_t)b * N_PTS + pid[r]) * D_FEAT;
        for (int c = t; c < 768; c += 256) xt[r * 772 + c] = src[c];
    }
    __syncthreads();
    if (isdet && t < 8) {
        float tot = dpart[0][t] + dpart[1][t] + dpart[2][t] + dpart[3][t];
        sdens[t] = 1.0f + (tot / 8192.0f) * 0.95f;
    }

    {
        int rp = t & 3;
        int jg = t >> 2;
        int r0 = rp * 2;
        if (jg * 4 < C) {
            float4 acc0[4], acc1[4];
#pragma unroll
            for (int a = 0; a < 4; a++) { acc0[a] = make_float4(0, 0, 0, 0); acc1[a] = make_float4(0, 0, 0, 0); }
            for (int k = 0; k < 768; k += 4) {
                float4 x0 = *(const float4*)&xt[r0 * 772 + k];
                float4 x1 = *(const float4*)&xt[(r0 + 1) * 772 + k];
#pragma unroll
                for (int a = 0; a < 4; a++) {
                    int j = jg * 4 + a;
                    float4 wv = *(const float4*)&W1[(size_t)j * 768 + k];
                    acc0[a].x = fmaf(wv.x, x0.x, acc0[a].x); acc0[a].y = fmaf(wv.y, x0.y, acc0[a].y);
                    acc0[a].z = fmaf(wv.z, x0.z, acc0[a].z); acc0[a].w = fmaf(wv.w, x0.w, acc0[a].w);
                    acc1[a].x = fmaf(wv.x, x1.x, acc1[a].x); acc1[a].y = fmaf(wv.y, x1.y, acc1[a].y);
                    acc1[a].z = fmaf(wv.z, x1.z, acc1[a].z); acc1[a].w = fmaf(wv.w, x1.w, acc1[a].w);
                }
            }
#pragma unroll
            for (int a = 0; a < 4; a++) {
                int j = jg * 4 + a;
                float bb = b1[j];
                float v0 = (acc0[a].x + acc0[a].y) + (acc0[a].z + acc0[a].w) + bb;
                float v1 = (acc1[a].x + acc1[a].y) + (acc1[a].z + acc1[a].w) + bb;
                h1s[r0 * 260 + j]       = fmaxf(v0, 0.f);
                h1s[(r0 + 1) * 260 + j] = fmaxf(v1, 0.f);
            }
        }
    }
    __syncthreads();

    if (t < 8 * S) {
        int r = t / S, s = t % S;
        float4 a = make_float4(0, 0, 0, 0);
        for (int k = 0; k < C; k += 4) {
            float4 wv = *(const float4*)&W2[s * C + k];
            float4 h = *(const float4*)&h1s[r * 260 + k];
            a.x = fmaf(wv.x, h.x, a.x); a.y = fmaf(wv.y, h.y, a.y);
            a.z = fmaf(wv.z, h.z, a.z); a.w = fmaf(wv.w, h.w, a.w);
        }
        float logit = (a.x + a.y) + (a.z + a.w) + b2[s];
        ps[r * 16 + s] = 1.0f / (1.0f + expf(-logit));
    }
    __syncthreads();
    if (t < 8) {
        float m = 0.f;
        for (int s = 0; s < S; s++) m += ps[t * 16 + s];
        m /= (float)S;
        float saf = isdet ? sdens[t] : safety_all[off + b * C + c0 + t];
        final_all[off + b * C + c0 + t] = m * saf;
    }
}

// ---------------- final MLP + LayerNorm, with per-block redundant top-k ----------------
__global__ __launch_bounds__(256) void final_kernel(
    const float* __restrict__ feat, const int* __restrict__ idx_all,
    const float* __restrict__ final_all,
    const float* __restrict__ pW1, const float* __restrict__ pb1,
    const float* __restrict__ pW2, const float* __restrict__ pb2,
    const float* __restrict__ lng, const float* __restrict__ lnb,
    float* __restrict__ out) {
    int bid = blockIdx.x;               // 40 blocks
    int b = bid / 20, pr = bid % 20;
    int t = threadIdx.x;
    __shared__ float xt[2 * 772];
    __shared__ float h1s[2 * 388];
    __shared__ float red[16];
    __shared__ int tokp[2];

    int scale = (pr < 8) ? 0 : (pr < 16) ? 1 : 2;
    int C    = (scale == 0) ? 256 : (scale == 1) ? 128 : 64;
    int off  = (scale == 0) ? 0 : (scale == 1) ? 512 : 768;
    int base = (scale == 0) ? 0 : (scale == 1) ? 8 : 16;   // in block units
    int r0 = (pr - base) * 2;           // rank of first token within scale

    if (t < 64) {                       // wave 0 does the top-k
        float v[4];
#pragma unroll
        for (int j = 0; j < 4; j++) {
            int ii = t + j * 64;
            v[j] = (ii < C) ? final_all[off + b * C + ii] : -INFINITY;
        }
        for (int s = 0; s <= r0 + 1; s++) {
            float bd = v[0]; int bj = 0;
#pragma unroll
            for (int j = 1; j < 4; j++) if (v[j] > bd) { bd = v[j]; bj = j; }
            int bi2 = t + bj * 64;
            float m = wred_max_f32(bd);          // scores > 0, identity 0 safe
            int cand = (bd == m) ? bi2 : 0x7fffffff;
            int wi = wred_min_i32(cand);         // first-index tie-break = lax.top_k
            if (t == (wi & 63)) {
#pragma unroll
                for (int j = 0; j < 4; j++) if (j == (wi >> 6)) v[j] = -INFINITY;
            }
            if (t == 0) {
                if (s == r0)     tokp[0] = idx_all[off + b * C + wi];
                if (s == r0 + 1) tokp[1] = idx_all[off + b * C + wi];
            }
        }
    }
    __syncthreads();

    for (int r = 0; r < 2; r++) {
        int p = tokp[r];
        const float* src = feat + ((size_t)b * N_PTS + p) * D_FEAT;
        for (int c = t; c < 768; c += 256) xt[r * 772 + c] = src[c];
    }
    __syncthreads();

    for (int u = t; u < 768; u += 256) {
        int j = u >> 1, r = u & 1;
        float4 a = make_float4(0, 0, 0, 0);
        for (int k = 0; k < 768; k += 4) {
            float4 wv = *(const float4*)&pW1[(size_t)j * 768 + k];
            float4 x = *(const float4*)&xt[r * 772 + k];
            a.x = fmaf(wv.x, x.x, a.x); a.y = fmaf(wv.y, x.y, a.y);
            a.z = fmaf(wv.z, x.z, a.z); a.w = fmaf(wv.w, x.w, a.w);
        }
        float v = (a.x + a.y) + (a.z + a.w) + pb1[j];
        h1s[r * 388 + j] = fmaxf(v, 0.f);
    }
    __syncthreads();

    for (int u = t; u < 1536; u += 256) {
        int o = u >> 1, r = u & 1;
        float4 a = make_float4(0, 0, 0, 0);
        for (int k = 0; k < 384; k += 4) {
            float4 wv = *(const float4*)&pW2[(size_t)o * 384 + k];
            float4 h = *(const float4*)&h1s[r * 388 + k];
            a.x = fmaf(wv.x, h.x, a.x); a.y = fmaf(wv.y, h.y, a.y);
            a.z = fmaf(wv.z, h.z, a.z); a.w = fmaf(wv.w, h.w, a.w);
        }
        xt[r * 772 + o] = (a.x + a.y) + (a.z + a.w) + pb2[o];
    }
    __syncthreads();

    for (int r = 0; r < 2; r++) {
        float s1 = 0.f, s2 = 0.f;
        for (int o = t; o < 768; o += 256) { float v = xt[r * 772 + o]; s1 += v; s2 += v * v; }
#pragma unroll
        for (int off2 = 32; off2 >= 1; off2 >>= 1) {
            s1 += __shfl_down(s1, off2, 64);
            s2 += __shfl_down(s2, off2, 64);
        }
        int lane = t & 63, wid = t >> 6;
        if (lane == 0) { red[wid * 2] = s1; red[wid * 2 + 1] = s2; }
        __syncthreads();
        float S1 = red[0] + red[2] + red[4] + red[6];
        float S2 = red[1] + red[3] + red[5] + red[7];
        float mu = S1 / 768.0f;
        float var = S2 / 768.0f - mu * mu;
        float inv = rsqrtf(var + 1e-5f);
        float* dst = out + ((size_t)b * 40 + pr * 2 + r) * 768;
        for (int o = t; o < 768; o += 256) {
            float v = xt[r * 772 + o];
            dst[o] = (v - mu) * inv * lng[o] + lnb[o];
        }
        __syncthreads();
    }
}

extern "C" void kernel_launch(void* const* d_in, const int* in_sizes, int n_in,
                              void* d_out, int out_size, void* d_ws, size_t ws_size,
                              hipStream_t stream) {
    const float* feat   = (const float*)d_in[0];
    const float* coords = (const float*)d_in[1];
    const float* gW1 = (const float*)d_in[2],  *gb1 = (const float*)d_in[3];
    const float* gW2 = (const float*)d_in[4],  *gb2 = (const float*)d_in[5];
    const float* cW1 = (const float*)d_in[6],  *cb1 = (const float*)d_in[7];
    const float* cW2 = (const float*)d_in[8],  *cb2 = (const float*)d_in[9];
    const float* dW1 = (const float*)d_in[10], *db1 = (const float*)d_in[11];
    const float* dW2 = (const float*)d_in[12], *db2 = (const float*)d_in[13];
    const float* pW1 = (const float*)d_in[14], *pb1 = (const float*)d_in[15];
    const float* pW2 = (const float*)d_in[16], *pb2 = (const float*)d_in[17];
    const float* lng = (const float*)d_in[18], *lnb = (const float*)d_in[19];
    float* out = (float*)d_out;

    int*   idx_all    = (int*)d_ws;               // 896 ints
    float* safety_all = (float*)d_ws + 896;       // 768 floats used
    float* final_all  = (float*)d_ws + 1792;      // 896 floats

    fps_kernel<<<2, 512, 0, stream>>>(coords, idx_all, safety_all);
    score_kernel<<<112, 256, 0, stream>>>(feat, coords, gW1, gb1, gW2, gb2, cW1, cb1, cW2, cb2,
                                          dW1, db1, dW2, db2, idx_all, safety_all, final_all);
    final_kernel<<<40, 256, 0, stream>>>(feat, idx_all, final_all, pW1, pb1, pW2, pb2, lng, lnb, out);
}

// Round 3
// 525.677 us; speedup vs baseline: 1.2167x; 1.0616x over previous
//
#include <hip/hip_runtime.h>
#include <math.h>

#define N_PTS 8192
#define D_FEAT 768

typedef float v2f __attribute__((ext_vector_type(2)));

// ---- wave64 reductions via DPP (row_shr 1,2,4,8 + row_bcast15, row_bcast31) ----
__device__ __forceinline__ float wred_max_f32(float x) {   // x >= 0 required (identity 0)
    int v = __float_as_int(x), o;
    o = __builtin_amdgcn_update_dpp(0, v, 0x111, 0xf, 0xf, false); v = __float_as_int(fmaxf(__int_as_float(v), __int_as_float(o)));
    o = __builtin_amdgcn_update_dpp(0, v, 0x112, 0xf, 0xf, false); v = __float_as_int(fmaxf(__int_as_float(v), __int_as_float(o)));
    o = __builtin_amdgcn_update_dpp(0, v, 0x114, 0xf, 0xf, false); v = __float_as_int(fmaxf(__int_as_float(v), __int_as_float(o)));
    o = __builtin_amdgcn_update_dpp(0, v, 0x118, 0xf, 0xf, false); v = __float_as_int(fmaxf(__int_as_float(v), __int_as_float(o)));
    o = __builtin_amdgcn_update_dpp(0, v, 0x142, 0xa, 0xf, false); v = __float_as_int(fmaxf(__int_as_float(v), __int_as_float(o)));
    o = __builtin_amdgcn_update_dpp(0, v, 0x143, 0xc, 0xf, false); v = __float_as_int(fmaxf(__int_as_float(v), __int_as_float(o)));
    return __int_as_float(__builtin_amdgcn_readlane(v, 63));
}
__device__ __forceinline__ int wred_min_i32(int x) {       // x >= 0 (identity INT_MAX)
    int v = x, o;
    o = __builtin_amdgcn_update_dpp(0x7fffffff, v, 0x111, 0xf, 0xf, false); v = (o < v) ? o : v;
    o = __builtin_amdgcn_update_dpp(0x7fffffff, v, 0x112, 0xf, 0xf, false); v = (o < v) ? o : v;
    o = __builtin_amdgcn_update_dpp(0x7fffffff, v, 0x114, 0xf, 0xf, false); v = (o < v) ? o : v;
    o = __builtin_amdgcn_update_dpp(0x7fffffff, v, 0x118, 0xf, 0xf, false); v = (o < v) ? o : v;
    o = __builtin_amdgcn_update_dpp(0x7fffffff, v, 0x142, 0xa, 0xf, false); v = (o < v) ? o : v;
    o = __builtin_amdgcn_update_dpp(0x7fffffff, v, 0x143, 0xc, 0xf, false); v = (o < v) ? o : v;
    return __builtin_amdgcn_readlane(v, 63);
}
__device__ __forceinline__ float wred_add_f32(float x) {   // identity 0
    int v = __float_as_int(x), o;
    o = __builtin_amdgcn_update_dpp(0, v, 0x111, 0xf, 0xf, false); v = __float_as_int(__int_as_float(v) + __int_as_float(o));
    o = __builtin_amdgcn_update_dpp(0, v, 0x112, 0xf, 0xf, false); v = __float_as_int(__int_as_float(v) + __int_as_float(o));
    o = __builtin_amdgcn_update_dpp(0, v, 0x114, 0xf, 0xf, false); v = __float_as_int(__int_as_float(v) + __int_as_float(o));
    o = __builtin_amdgcn_update_dpp(0, v, 0x118, 0xf, 0xf, false); v = __float_as_int(__int_as_float(v) + __int_as_float(o));
    o = __builtin_amdgcn_update_dpp(0, v, 0x142, 0xa, 0xf, false); v = __float_as_int(__int_as_float(v) + __int_as_float(o));
    o = __builtin_amdgcn_update_dpp(0, v, 0x143, 0xc, 0xf, false); v = __float_as_int(__int_as_float(v) + __int_as_float(o));
    return __int_as_float(__builtin_amdgcn_readlane(v, 63));
}

// u64 max-merge DPP step (kept for the cross-wave 8-record combine).
#define DPP64_STEP(cur, ctrl, rmask)                                                        \
    {                                                                                       \
        unsigned _h = (unsigned)__builtin_amdgcn_update_dpp(0, (int)(unsigned)((cur) >> 32), ctrl, rmask, 0xf, false); \
        unsigned _l = (unsigned)__builtin_amdgcn_update_dpp(0, (int)(unsigned)(cur), ctrl, rmask, 0xf, false);         \
        unsigned long long _o = ((unsigned long long)_h << 32) | _l;                        \
        cur = (_o > (cur)) ? _o : (cur);                                                    \
    }

// ---------------- FPS + global/component safety: one block per batch ----------------
// ROUND 11 delta vs r10 (selection-exact): the per-wave 6-step DPP64 chain is
// replaced by f32 wred_max + ballot. Unique-max case (overwhelmingly common):
// winner index via one readlane. Tie case: wred_min over matching lanes' bi
// == (value desc, index asc) semantics, exactly as the u64 key chain.
__global__ __launch_bounds__(512, 2) __attribute__((amdgpu_waves_per_eu(2)))
void fps_kernel(const float* __restrict__ coords,
                int* __restrict__ idx_all,
                float* __restrict__ safety_all) {
#pragma clang fp contract(off)
    const int b = blockIdx.x;         // 0..1
    const int t = threadIdx.x;        // 0..511
    const float* cb = coords + (size_t)b * N_PTS * 3;

    v2f px2[8], py2[8], pz2[8], m2p[8];
#pragma unroll
    for (int j = 0; j < 8; j++) {
        int p0 = t + (2 * j) * 512, p1 = t + (2 * j + 1) * 512;
        px2[j].x = cb[p0 * 3 + 0]; px2[j].y = cb[p1 * 3 + 0];
        py2[j].x = cb[p0 * 3 + 1]; py2[j].y = cb[p1 * 3 + 1];
        pz2[j].x = cb[p0 * 3 + 2]; pz2[j].y = cb[p1 * 3 + 2];
        m2p[j].x = INFINITY; m2p[j].y = INFINITY;
    }
    __shared__ float cbl4[N_PTS * 4];           // 128 KiB coord table, float4 stride
    __shared__ unsigned long long skey[2][8];
    __shared__ int sel[256];
    __shared__ float r1s[8], r2s[8];
#pragma unroll
    for (int j = 0; j < 8; j++) {
        int p0 = t + (2 * j) * 512, p1 = t + (2 * j + 1) * 512;
        *(float4*)&cbl4[p0 * 4] = make_float4(px2[j].x, py2[j].x, pz2[j].x, 0.f);
        *(float4*)&cbl4[p1 * 4] = make_float4(px2[j].y, py2[j].y, pz2[j].y, 0.f);
    }
    if (t == 0) sel[0] = 0;
    float lx = cb[0], ly = cb[1], lz = cb[2];   // center 0 (uniform broadcast load)
    __syncthreads();

    const int lane = t & 63, w = t >> 6;        // wave 0..7
    for (int i = 1; i < 256; i++) {
        // --- branch-free d2-domain update, packed f32x2 (numpy op order per half) ---
        v2f Lx = {lx, lx}, Ly = {ly, ly}, Lz = {lz, lz};
#pragma unroll
        for (int j = 0; j < 8; j++) {
            v2f dx = px2[j] - Lx, dy = py2[j] - Ly, dz = pz2[j] - Lz;
            v2f d2 = dx * dx + dy * dy + dz * dz;      // ((dx^2+dy^2)+dz^2), no fma
            m2p[j] = __builtin_elementwise_min(m2p[j], d2);
        }
        // --- per-thread max via balanced tree (order-independent for non-NaN) ---
        v2f q[4];
#pragma unroll
        for (int j = 0; j < 4; j++) q[j] = __builtin_elementwise_max(m2p[j], m2p[j + 4]);
        q[0] = __builtin_elementwise_max(q[0], q[2]);
        q[1] = __builtin_elementwise_max(q[1], q[3]);
        q[0] = __builtin_elementwise_max(q[0], q[1]);
        float c2 = fmaxf(q[0].x, q[0].y);
        // --- first index achieving c2: parallel match + min tree (depth 5) ---
        int ci[8];
#pragma unroll
        for (int j = 0; j < 8; j++) {
            int a  = (m2p[j].x == c2) ? (2 * j)     : 0x7fff;
            int bb = (m2p[j].y == c2) ? (2 * j + 1) : 0x7fff;
            ci[j] = (a < bb) ? a : bb;
        }
#pragma unroll
        for (int j = 0; j < 4; j++) ci[j] = min(ci[j], ci[j + 4]);
        int bk = min(min(ci[0], ci[1]), min(ci[2], ci[3]));
        // sqrt-collapse guard (per-thread band, ballot-summed; conservative).
        float thi = c2 * 0.9999995f;
        int tot = 0;
#pragma unroll
        for (int j = 0; j < 8; j++) {
            tot += __popcll(__ballot(m2p[j].x >= thi));
            tot += __popcll(__ballot(m2p[j].y >= thi));
        }
        float smax;
        if (tot > 64) {               // rare wave-uniform slow path (exact)
            smax = -1.f; bk = 0;
#pragma unroll
            for (int k = 0; k < 16; k++) {
                float mk = (k & 1) ? m2p[k >> 1].y : m2p[k >> 1].x;   // static idx (unrolled)
                float s = sqrtf(mk);
                if (s > smax) { smax = s; bk = k; }
            }
        } else {
            smax = sqrtf(c2);         // one correctly-rounded sqrt per thread
        }
        int bi = t + bk * 512;
        // --- wave argmax: f32 max + ballot; tie -> min-index reduce (exact) ---
        float mred = wred_max_f32(smax);
        unsigned long long ball = __ballot(smax == mred);
        int bi_win;
        if (__popcll(ball) == 1) {                       // unique max (common)
            int ls = (int)__builtin_ctzll(ball);         // SALU
            bi_win = __builtin_amdgcn_readlane(bi, ls);
        } else {                                         // sqrt-tie across lanes
            int cand = (smax == mred) ? bi : 0x7fffffff;
            bi_win = wred_min_i32(cand);                 // first index = reference
        }
        unsigned long long key = ((unsigned long long)__float_as_uint(mred) << 32)
                               | (unsigned)(0xFFFFFFFFu - (unsigned)bi_win);
        if (lane == 63) skey[i & 1][w] = key;
        __syncthreads();   // LDS-only before barrier -> cheap lgkm drain
        const int par = i & 1;
        // --- read 8 wave records; speculatively load ALL candidates' coords (LDS) ---
        unsigned long long k8 = skey[par][lane & 7];
        int cidx = (int)(0xFFFFFFFFu - (unsigned)k8);   // candidate of record lane&7
        float spec = 0.f;
        if (lane < 24) spec = cbl4[cidx * 4 + (lane >> 3)];  // ds_read, covers 8x xyz
        // --- combine over 8 records (overlaps the LDS load) ---
        DPP64_STEP(k8, 0x111, 0xf)
        DPP64_STEP(k8, 0x112, 0xf)
        DPP64_STEP(k8, 0x114, 0xf)     // lane 7 = max of records 0..7
        unsigned klo = (unsigned)__builtin_amdgcn_readlane((int)(unsigned)k8, 7);
        int fbi = (int)(0xFFFFFFFFu - klo);             // uniform (SGPR)
        int ww = (fbi & 511) >> 6;                      // winning wave / record 0..7
        // winner coords from the speculative lanes: rec=ww, comp c at lane c*8+ww
        lx = __int_as_float(__builtin_amdgcn_readlane(__float_as_int(spec), ww));
        ly = __int_as_float(__builtin_amdgcn_readlane(__float_as_int(spec), 8 + ww));
        lz = __int_as_float(__builtin_amdgcn_readlane(__float_as_int(spec), 16 + ww));
        if (t == 0) sel[i] = fbi;     // LDS only
        // NOTE: no explicit zeroing of the winner: next update gives d2=0 exactly.
    }

    // ---- tail: write indices once (oc/od are prefixes of og) ----
    __syncthreads();
    if (t < 256) {
        int v = sel[t];
        idx_all[b * 256 + t] = v;                    // og
        if (t < 128) idx_all[512 + b * 128 + t] = v; // oc
        if (t < 64)  idx_all[768 + b * 64 + t] = v;  // od
    }

    // ---- tail: global & component safety (z in registers; k-order per thread) ----
    float s1 = 0.f, s2 = 0.f;
#pragma unroll
    for (int j = 0; j < 8; j++) {
        s1 += pz2[j].x; s2 += pz2[j].x * pz2[j].x;   // k = 2j
        s1 += pz2[j].y; s2 += pz2[j].y * pz2[j].y;   // k = 2j+1
    }
    s1 = wred_add_f32(s1);
    s2 = wred_add_f32(s2);
    if (lane == 0) { r1s[w] = s1; r2s[w] = s2; }
    __syncthreads();
    float S1 = ((r1s[0] + r1s[1]) + (r1s[2] + r1s[3])) + ((r1s[4] + r1s[5]) + (r1s[6] + r1s[7]));
    float S2 = ((r2s[0] + r2s[1]) + (r2s[2] + r2s[3])) + ((r2s[4] + r2s[5]) + (r2s[6] + r2s[7]));
    float mean = S1 / 8192.0f;
    float var1 = (S2 - S1 * S1 / 8192.0f) / 8191.0f;     // ddof=1
    float scomp = 1.0f + expf(-var1 / 0.1f) * 0.9f;      // component safety
    if (t < 256) {
        int p = sel[t];
        float z = cbl4[p * 4 + 2];                       // bit-identical copy of cb[p*3+2]
        safety_all[b * 256 + t] = 1.0f + (1.0f / (1.0f + expf(-((z - mean) / 5.0f)))) * 0.95f;
        if (t < 128) safety_all[512 + b * 128 + t] = scomp;
    }
}

// ---------------- per-scale score MLP (+ detail density folded in) ----------------
// ROUND 11: W1 GEMM k-split. Thread (jg = t>>2, rp = t&3) owns RT = C/64 rows
// and k-chunk [rp*192, rp*192+192), accumulating partials for ALL 8 tokens.
// Every W1 element is read exactly ONCE per block (was 4x) -> per-block L2
// ingest 3.1 MB -> 0.79 MB. Partials reduced via LDS: (p0+p1)+(p2+p3)+bias.
#define W1_GEMM(RT)                                                            \
  {                                                                            \
    const int jg = t >> 2, rp = t & 3;                                         \
    const float* wb = W1 + (size_t)(jg * RT) * 768 + rp * 192;                 \
    float4 acc[RT][8];                                                         \
    _Pragma("unroll") for (int a = 0; a < RT; a++)                             \
      _Pragma("unroll") for (int r = 0; r < 8; r++)                            \
        acc[a][r] = make_float4(0.f, 0.f, 0.f, 0.f);                           \
    for (int s = 0; s < 192; s += 4) {                                         \
      float4 xv[8];                                                            \
      _Pragma("unroll") for (int r = 0; r < 8; r++)                            \
        xv[r] = *(const float4*)&xt[r * 772 + rp * 192 + s];                   \
      _Pragma("unroll") for (int a = 0; a < RT; a++) {                         \
        float4 wv = *(const float4*)&wb[(size_t)a * 768 + s];                  \
        _Pragma("unroll") for (int r = 0; r < 8; r++) {                        \
          acc[a][r].x = fmaf(wv.x, xv[r].x, acc[a][r].x);                      \
          acc[a][r].y = fmaf(wv.y, xv[r].y, acc[a][r].y);                      \
          acc[a][r].z = fmaf(wv.z, xv[r].z, acc[a][r].z);                      \
          acc[a][r].w = fmaf(wv.w, xv[r].w, acc[a][r].w);                      \
        }                                                                      \
      }                                                                        \
    }                                                                          \
    _Pragma("unroll") for (int a = 0; a < RT; a++)                             \
      _Pragma("unroll") for (int r = 0; r < 8; r++)                            \
        part[rp * 2048 + (jg * RT + a) * 8 + r] =                              \
            (acc[a][r].x + acc[a][r].y) + (acc[a][r].z + acc[a][r].w);         \
  }

__global__ __launch_bounds__(256) void score_kernel(
    const float* __restrict__ feat, const float* __restrict__ coords,
    const float* __restrict__ gW1, const float* __restrict__ gb1,
    const float* __restrict__ gW2, const float* __restrict__ gb2,
    const float* __restrict__ cW1, const float* __restrict__ cb1,
    const float* __restrict__ cW2, const float* __restrict__ cb2,
    const float* __restrict__ dW1, const float* __restrict__ db1,
    const float* __restrict__ dW2, const float* __restrict__ db2,
    const int* __restrict__ idx_all, const float* __restrict__ safety_all,
    float* __restrict__ final_all) {
    int bid = blockIdx.x;
    int b, c0, C, S, off;
    const float *W1, *b1, *W2, *b2;
    if (bid < 64)      { C = 256; S = 16; W1 = gW1; b1 = gb1; W2 = gW2; b2 = gb2; b = bid >> 5; c0 = (bid & 31) * 8; off = 0; }
    else if (bid < 96) { int r = bid - 64; C = 128; S = 16; W1 = cW1; b1 = cb1; W2 = cW2; b2 = cb2; b = r >> 4; c0 = (r & 15) * 8; off = 512; }
    else               { int r = bid - 96; C = 64;  S = 8;  W1 = dW1; b1 = db1; W2 = dW2; b2 = db2; b = r >> 3; c0 = (r & 7) * 8; off = 768; }
    const bool isdet = (bid >= 96);

    __shared__ float xt[8 * 772];
    __shared__ float h1s[8 * 260];
    __shared__ float part[4 * 2048];
    __shared__ float ps[8 * 16];
    __shared__ int pid[8];
    __shared__ float dpart[4][8];
    __shared__ float sdens[8];
    const int t = threadIdx.x;
    if (t < 8) pid[t] = idx_all[off + b * C + c0 + t];
    __syncthreads();

    if (isdet) {
#pragma clang fp contract(off)
        float cx[8], cy[8], cz[8], cc[8];
#pragma unroll
        for (int c = 0; c < 8; c++) {
            const float* cp = coords + ((size_t)b * N_PTS + pid[c]) * 3;
            cx[c] = cp[0]; cy[c] = cp[1]; cz[c] = cp[2];
            cc[c] = cx[c] * cx[c] + cy[c] * cy[c] + cz[c] * cz[c];
        }
        int cnt[8];
#pragma unroll
        for (int c = 0; c < 8; c++) cnt[c] = 0;
        const float* cbl = coords + (size_t)b * N_PTS * 3;
        for (int k = 0; k < 32; k++) {
            int q = t + k * 256;
            float x = cbl[q * 3], y = cbl[q * 3 + 1], z = cbl[q * 3 + 2];
            float pp = x * x + y * y + z * z;
#pragma unroll
            for (int c = 0; c < 8; c++) {
                float dot = cx[c] * x + cy[c] * y + cz[c] * z;
                float d2 = (cc[c] + pp) - 2.0f * dot;   // same formula/order as reference
                if (d2 < 0.25f) cnt[c]++;
            }
        }
        int wv = t >> 6;
#pragma unroll
        for (int c = 0; c < 8; c++) {
            float s = wred_add_f32((float)cnt[c]);      // integer counts: exact in f32
            if ((t & 63) == 0) dpart[wv][c] = s;
        }
    }

    for (int r = 0; r < 8; r++) {
        const float* src = feat + ((size_t)b * N_PTS + pid[r]) * D_FEAT;
        for (int c = t; c < 768; c += 256) xt[r * 772 + c] = src[c];
    }
    __syncthreads();
    if (isdet && t < 8) {
        float tot = dpart[0][t] + dpart[1][t] + dpart[2][t] + dpart[3][t];
        sdens[t] = 1.0f + (tot / 8192.0f) * 0.95f;
    }

    if (C == 256)      W1_GEMM(4)
    else if (C == 128) W1_GEMM(2)
    else               W1_GEMM(1)
    __syncthreads();
    for (int u = t; u < C * 8; u += 256) {
        int row = u >> 3;
        float sum = (part[u] + part[2048 + u]) + (part[4096 + u] + part[6144 + u]) + b1[row];
        h1s[(u & 7) * 260 + row] = fmaxf(sum, 0.f);
    }
    __syncthreads();

    if (t < 8 * S) {
        int r = t / S, s = t % S;
        float4 a = make_float4(0, 0, 0, 0);
        for (int k = 0; k < C; k += 4) {
            float4 wv = *(const float4*)&W2[s * C + k];
            float4 h = *(const float4*)&h1s[r * 260 + k];
            a.x = fmaf(wv.x, h.x, a.x); a.y = fmaf(wv.y, h.y, a.y);
            a.z = fmaf(wv.z, h.z, a.z); a.w = fmaf(wv.w, h.w, a.w);
        }
        float logit = (a.x + a.y) + (a.z + a.w) + b2[s];
        ps[r * 16 + s] = 1.0f / (1.0f + expf(-logit));
    }
    __syncthreads();
    if (t < 8) {
        float m = 0.f;
        for (int s = 0; s < S; s++) m += ps[t * 16 + s];
        m /= (float)S;
        float saf = isdet ? sdens[t] : safety_all[off + b * C + c0 + t];
        final_all[off + b * C + c0 + t] = m * saf;
    }
}

// ---------------- final pipeline: topk -> h -> pre -> LN ----------------
// ROUND 11: replaces the 40-block final_kernel whose every block streamed ALL
// of pW1+pW2 (2.36 MB) from L2. Now partitioned by OUTPUT rows so per-block
// weight bytes are ~25-50 KB, with broadcast-friendly addressing.

__global__ __launch_bounds__(64) void topk_kernel(
    const float* __restrict__ final_all, const int* __restrict__ idx_all,
    int* __restrict__ tok) {
    int bid = blockIdx.x;               // 0..5 = batch*3 + scale
    int b = bid / 3, sc = bid % 3;
    int C    = (sc == 0) ? 256 : (sc == 1) ? 128 : 64;
    int off  = (sc == 0) ? 0 : (sc == 1) ? 512 : 768;
    int base = (sc == 0) ? 0 : (sc == 1) ? 16 : 32;
    int S    = (sc == 2) ? 8 : 16;
    int t = threadIdx.x;
    float v[4];
#pragma unroll
    for (int j = 0; j < 4; j++) {
        int ii = t + j * 64;
        v[j] = (ii < C) ? final_all[off + b * C + ii] : -INFINITY;
    }
    for (int s = 0; s < S; s++) {
        float bd = v[0]; int bj = 0;
#pragma unroll
        for (int j = 1; j < 4; j++) if (v[j] > bd) { bd = v[j]; bj = j; }
        int bi2 = t + bj * 64;
        float m = wred_max_f32(bd);          // scores > 0, identity 0 safe
        int cand = (bd == m) ? bi2 : 0x7fffffff;
        int wi = wred_min_i32(cand);         // first-index tie-break = lax.top_k
        if (t == (wi & 63)) {
#pragma unroll
            for (int j = 0; j < 4; j++) if (j == (wi >> 6)) v[j] = -INFINITY;
        }
        if (t == 0) tok[b * 40 + base + s] = idx_all[off + b * C + wi];
    }
}

// h[b][tk][j] = relu(feat[tok] . pW1[j] + pb1[j]);  8 rows x 40 tokens / block
__global__ __launch_bounds__(320) void h_kernel(
    const float* __restrict__ feat, const int* __restrict__ tok,
    const float* __restrict__ pW1, const float* __restrict__ pb1,
    float* __restrict__ h_buf) {
    int bid = blockIdx.x;               // 96 = 2 batches x 48 j-slices
    int b = bid / 48, js = bid % 48;
    int t = threadIdx.x;                // 320 = 8 j x 40 tk
    int tk = t % 40, jr = t / 40;
    int j = js * 8 + jr;
    int p = tok[b * 40 + tk];
    const float* x = feat + ((size_t)b * N_PTS + p) * D_FEAT;
    const float* wrow = pW1 + (size_t)j * 768;
    float4 a = make_float4(0, 0, 0, 0);
    for (int k = 0; k < 768; k += 4) {
        float4 wv = *(const float4*)&wrow[k];
        float4 xv = *(const float4*)&x[k];
        a.x = fmaf(wv.x, xv.x, a.x); a.y = fmaf(wv.y, xv.y, a.y);
        a.z = fmaf(wv.z, xv.z, a.z); a.w = fmaf(wv.w, xv.w, a.w);
    }
    float v = (a.x + a.y) + (a.z + a.w) + pb1[j];
    h_buf[((size_t)b * 40 + tk) * 384 + j] = fmaxf(v, 0.f);
}

// pre[b][tk][o] = h[b][tk] . pW2[o] + pb2[o];  8 rows x 40 tokens / block
__global__ __launch_bounds__(320) void out_kernel(
    const float* __restrict__ h_buf,
    const float* __restrict__ pW2, const float* __restrict__ pb2,
    float* __restrict__ pre_buf) {
    int bid = blockIdx.x;               // 192 = 2 batches x 96 o-slices
    int b = bid / 96, os = bid % 96;
    int t = threadIdx.x;                // 320 = 8 o x 40 tk
    int tk = t % 40, orr = t / 40;
    int o = os * 8 + orr;
    const float* h = h_buf + ((size_t)b * 40 + tk) * 384;
    const float* wrow = pW2 + (size_t)o * 384;
    float4 a = make_float4(0, 0, 0, 0);
    for (int k = 0; k < 384; k += 4) {
        float4 wv = *(const float4*)&wrow[k];
        float4 hv = *(const float4*)&h[k];
        a.x = fmaf(wv.x, hv.x, a.x); a.y = fmaf(wv.y, hv.y, a.y);
        a.z = fmaf(wv.z, hv.z, a.z); a.w = fmaf(wv.w, hv.w, a.w);
    }
    pre_buf[((size_t)b * 40 + tk) * 768 + o] = (a.x + a.y) + (a.z + a.w) + pb2[o];
}

// LayerNorm per token row (one wave per token)
__global__ __launch_bounds__(64) void ln_kernel(
    const float* __restrict__ pre_buf,
    const float* __restrict__ lng, const float* __restrict__ lnb,
    float* __restrict__ out) {
    int bid = blockIdx.x;               // 80 = 2 batches x 40 tokens
    int lane = threadIdx.x;
    const float* row = pre_buf + (size_t)bid * 768;
    float v[12], s1 = 0.f, s2 = 0.f;
#pragma unroll
    for (int i = 0; i < 12; i++) {
        v[i] = row[lane + i * 64];
        s1 += v[i]; s2 += v[i] * v[i];
    }
    s1 = wred_add_f32(s1);
    s2 = wred_add_f32(s2);
    float mu = s1 / 768.0f;
    float var = s2 / 768.0f - mu * mu;
    float inv = rsqrtf(var + 1e-5f);
    float* dst = out + (size_t)bid * 768;
#pragma unroll
    for (int i = 0; i < 12; i++) {
        int o = lane + i * 64;
        dst[o] = (v[i] - mu) * inv * lng[o] + lnb[o];
    }
}

extern "C" void kernel_launch(void* const* d_in, const int* in_sizes, int n_in,
                              void* d_out, int out_size, void* d_ws, size_t ws_size,
                              hipStream_t stream) {
    const float* feat   = (const float*)d_in[0];
    const float* coords = (const float*)d_in[1];
    const float* gW1 = (const float*)d_in[2],  *gb1 = (const float*)d_in[3];
    const float* gW2 = (const float*)d_in[4],  *gb2 = (const float*)d_in[5];
    const float* cW1 = (const float*)d_in[6],  *cb1 = (const float*)d_in[7];
    const float* cW2 = (const float*)d_in[8],  *cb2 = (const float*)d_in[9];
    const float* dW1 = (const float*)d_in[10], *db1 = (const float*)d_in[11];
    const float* dW2 = (const float*)d_in[12], *db2 = (const float*)d_in[13];
    const float* pW1 = (const float*)d_in[14], *pb1 = (const float*)d_in[15];
    const float* pW2 = (const float*)d_in[16], *pb2 = (const float*)d_in[17];
    const float* lng = (const float*)d_in[18], *lnb = (const float*)d_in[19];
    float* out = (float*)d_out;

    int*   idx_all    = (int*)d_ws;               // 896 ints
    float* safety_all = (float*)d_ws + 896;       // 768 floats used
    float* final_all  = (float*)d_ws + 1792;      // 896 floats
    int*   tok        = (int*)d_ws + 2688;        // 80 ints
    float* h_buf      = (float*)d_ws + 2816;      // 80*384 = 30720 floats
    float* pre_buf    = (float*)d_ws + 33536;     // 80*768 = 61440 floats (end ~371 KB)

    fps_kernel<<<2, 512, 0, stream>>>(coords, idx_all, safety_all);
    score_kernel<<<112, 256, 0, stream>>>(feat, coords, gW1, gb1, gW2, gb2, cW1, cb1, cW2, cb2,
                                          dW1, db1, dW2, db2, idx_all, safety_all, final_all);
    topk_kernel<<<6, 64, 0, stream>>>(final_all, idx_all, tok);
    h_kernel<<<96, 320, 0, stream>>>(feat, tok, pW1, pb1, h_buf);
    out_kernel<<<192, 320, 0, stream>>>(h_buf, pW2, pb2, pre_buf);
    ln_kernel<<<80, 64, 0, stream>>>(pre_buf, lng, lnb, out);
}